// Round 3
// baseline (267.092 us; speedup 1.0000x reference)
//
#include <hip/hip_runtime.h>

#define NR 512
#define NZ 512
#define P_ELEMS ((NR - 1) * NZ)   // 511*512 records
#define BLOCK 256
#define VPT 4                     // float4 groups per thread -> 16 queries/thread

typedef float vf4 __attribute__((ext_vector_type(4)));
typedef unsigned uv2 __attribute__((ext_vector_type(2)));

// ---- bf16 packing helpers ----
__device__ __forceinline__ unsigned bf16rne(float f) {
    unsigned u = __float_as_uint(f);
    return (u + 0x7FFFu + ((u >> 16) & 1u)) >> 16;   // round-to-nearest-even
}
__device__ __forceinline__ unsigned pack2(float lo, float hi) {
    return bf16rne(lo) | (bf16rne(hi) << 16);
}

// Pb[ir*NZ+iz] = { pack(Q11,Q21), pack(Q12,Q22) }
//   Q11=tt[ir,iz] Q21=tt[ir+1,iz] Q12=tt[ir,iz+1] Q22=tt[ir+1,iz+1]
__global__ void __launch_bounds__(256) build_bf16(
    const float* __restrict__ tt, uv2* __restrict__ Pb) {
    int i = blockIdx.x * 256 + threadIdx.x;
    if (i >= P_ELEMS) return;
    int ir = i >> 9;              // NZ = 512
    int iz = i & 511;
    int izc = min(iz, NZ - 2);    // slot iz=511 never queried; avoid OOB
    float q11 = tt[(ir << 9) + izc];
    float q12 = tt[(ir << 9) + izc + 1];
    float q21 = tt[((ir + 1) << 9) + izc];
    float q22 = tt[((ir + 1) << 9) + izc + 1];
    uv2 v;
    v.x = pack2(q11, q21);
    v.y = pack2(q12, q22);
    Pb[i] = v;
}

// L1-bypassing 8B gather: agent-scope relaxed load emits
// global_load_dwordx2 with sc0 (glc semantic) -> cannot be served by the
// non-coherent per-CU L1, so no tag lookup / MSHR / 64B line fill; the
// request queues straight to L2 and returns exactly 8B.
__device__ __forceinline__ uv2 gather_l2(const uv2* __restrict__ Pb, int idx) {
    unsigned long long v = __hip_atomic_load(
        reinterpret_cast<const unsigned long long*>(Pb) + idx,
        __ATOMIC_RELAXED, __HIP_MEMORY_SCOPE_AGENT);
    uv2 g;
    g.x = (unsigned)v;
    g.y = (unsigned)(v >> 32);
    return g;
}

// trunc-cast == floor for rr >= 0; for rr < 0 both paths clamp to 0 and the
// weight formula matches the reference's clipped-index semantics either way.
__device__ __forceinline__ int cell_addr(float rr, float zz) {
    int ir0 = min(max((int)rr, 0), NR - 2);
    int iz0 = min(max((int)zz, 0), NZ - 2);
    return (ir0 << 9) + iz0;
}

__device__ __forceinline__ float combine(float rr, float zz, uv2 g) {
    int ir0 = min(max((int)rr, 0), NR - 2);
    int iz0 = min(max((int)zz, 0), NZ - 2);
    float dx = rr - (float)ir0;
    float dz = zz - (float)iz0;
    float wx = 1.0f - dx;
    float wz = 1.0f - dz;
    float f11 = __uint_as_float(g.x << 16);
    float f21 = __uint_as_float(g.x & 0xFFFF0000u);
    float f12 = __uint_as_float(g.y << 16);
    float f22 = __uint_as_float(g.y & 0xFFFF0000u);
    return wx * (f11 * wz + f12 * dz) + dx * (f21 * wz + f22 * dz);
}

__global__ void __launch_bounds__(BLOCK, 4) interp_bf16(
    const float* __restrict__ r, const float* __restrict__ z,
    const uv2* __restrict__ Pb, float* __restrict__ out, int nvec) {
    const int tid = threadIdx.x;
    const int base = blockIdx.x * (BLOCK * VPT) + tid;
    const bool full = (blockIdx.x + 1) * (BLOCK * VPT) <= nvec;

    if (full) {
        // Phase 0: stream in 16 queries (nontemporal: don't pollute L2,
        // keep the gather table resident there).
        vf4 rv[VPT], zv[VPT];
#pragma unroll
        for (int k = 0; k < VPT; ++k) {
            rv[k] = __builtin_nontemporal_load(
                reinterpret_cast<const vf4*>(r) + base + k * BLOCK);
            zv[k] = __builtin_nontemporal_load(
                reinterpret_cast<const vf4*>(z) + base + k * BLOCK);
        }
        // Phase 1: issue ALL 16 gathers back-to-back, L1-bypassed.
        uv2 g[VPT][4];
#pragma unroll
        for (int k = 0; k < VPT; ++k) {
            g[k][0] = gather_l2(Pb, cell_addr(rv[k].x, zv[k].x));
            g[k][1] = gather_l2(Pb, cell_addr(rv[k].y, zv[k].y));
            g[k][2] = gather_l2(Pb, cell_addr(rv[k].z, zv[k].z));
            g[k][3] = gather_l2(Pb, cell_addr(rv[k].w, zv[k].w));
        }
        // Phase 2: recompute weights (cheap VALU) and combine.
#pragma unroll
        for (int k = 0; k < VPT; ++k) {
            vf4 o;
            o.x = combine(rv[k].x, zv[k].x, g[k][0]);
            o.y = combine(rv[k].y, zv[k].y, g[k][1]);
            o.z = combine(rv[k].z, zv[k].z, g[k][2]);
            o.w = combine(rv[k].w, zv[k].w, g[k][3]);
            __builtin_nontemporal_store(
                o, reinterpret_cast<vf4*>(out) + base + k * BLOCK);
        }
    } else {
#pragma unroll
        for (int k = 0; k < VPT; ++k) {
            const int gv = base + k * BLOCK;
            if (gv < nvec) {
                vf4 rv = reinterpret_cast<const vf4*>(r)[gv];
                vf4 zv = reinterpret_cast<const vf4*>(z)[gv];
                uv2 g0 = gather_l2(Pb, cell_addr(rv.x, zv.x));
                uv2 g1 = gather_l2(Pb, cell_addr(rv.y, zv.y));
                uv2 g2 = gather_l2(Pb, cell_addr(rv.z, zv.z));
                uv2 g3 = gather_l2(Pb, cell_addr(rv.w, zv.w));
                vf4 o;
                o.x = combine(rv.x, zv.x, g0);
                o.y = combine(rv.y, zv.y, g1);
                o.z = combine(rv.z, zv.z, g2);
                o.w = combine(rv.w, zv.w, g3);
                reinterpret_cast<vf4*>(out)[gv] = o;
            }
        }
    }
}

// ---- exact-fp32 scalar tail + fallback path ----
__device__ __forceinline__ float interp_direct(float rr, float zz,
                                               const float* __restrict__ tt) {
    int ir0 = (int)floorf(rr);
    int iz0 = (int)floorf(zz);
    ir0 = min(max(ir0, 0), NR - 2);
    iz0 = min(max(iz0, 0), NZ - 2);
    float dx = rr - (float)ir0, wx = 1.0f - dx;
    float dz = zz - (float)iz0, wz = 1.0f - dz;
    int b = (ir0 << 9) + iz0;
    float Q11 = tt[b], Q12 = tt[b + 1], Q21 = tt[b + NZ], Q22 = tt[b + NZ + 1];
    return (Q11 * wz + Q12 * dz) * wx + (Q21 * wz + Q22 * dz) * dx;
}

__global__ void tail_direct(const float* __restrict__ r, const float* __restrict__ z,
                            const float* __restrict__ tt, float* __restrict__ out,
                            int start, int n) {
    int j = start + blockIdx.x * blockDim.x + threadIdx.x;
    if (j < n) out[j] = interp_direct(r[j], z[j], tt);
}

__global__ void __launch_bounds__(256) interp_direct_kernel(
    const float* __restrict__ r, const float* __restrict__ z,
    const float* __restrict__ tt, float* __restrict__ out, int n4) {
    int i = blockIdx.x * blockDim.x + threadIdx.x;
    if (i < n4) {
        vf4 rv = reinterpret_cast<const vf4*>(r)[i];
        vf4 zv = reinterpret_cast<const vf4*>(z)[i];
        vf4 o;
        o.x = interp_direct(rv.x, zv.x, tt);
        o.y = interp_direct(rv.y, zv.y, tt);
        o.z = interp_direct(rv.z, zv.z, tt);
        o.w = interp_direct(rv.w, zv.w, tt);
        reinterpret_cast<vf4*>(out)[i] = o;
    }
}

extern "C" void kernel_launch(void* const* d_in, const int* in_sizes, int n_in,
                              void* d_out, int out_size, void* d_ws, size_t ws_size,
                              hipStream_t stream) {
    const float* r  = (const float*)d_in[0];
    const float* z  = (const float*)d_in[1];
    const float* tt = (const float*)d_in[2];
    float* out = (float*)d_out;
    const int n = in_sizes[0];
    const int nvec = n / 4;
    const int tail = n - nvec * 4;

    const size_t need = (size_t)P_ELEMS * sizeof(uv2);   // ~2.09 MB
    if (ws_size >= need) {
        uv2* Pb = (uv2*)d_ws;
        build_bf16<<<(P_ELEMS + 255) / 256, 256, 0, stream>>>(tt, Pb);
        const int blocks = (nvec + BLOCK * VPT - 1) / (BLOCK * VPT);
        interp_bf16<<<blocks, BLOCK, 0, stream>>>(r, z, Pb, out, nvec);
    } else {
        interp_direct_kernel<<<(nvec + 255) / 256, 256, 0, stream>>>(r, z, tt, out, nvec);
    }
    if (tail > 0)
        tail_direct<<<1, 64, 0, stream>>>(r, z, tt, out, nvec * 4, n);
}

// Round 4
// 260.701 us; speedup vs baseline: 1.0245x; 1.0245x over previous
//
#include <hip/hip_runtime.h>

#define NR 512
#define NZ 512
#define P_ELEMS ((NR - 1) * NZ)   // 511*512 records
#define BLOCK 256
#define VPT 4                     // float4 groups per thread -> 16 queries/thread

typedef float vf4 __attribute__((ext_vector_type(4)));
typedef unsigned uv2 __attribute__((ext_vector_type(2)));

// ---- bf16 packing helpers ----
__device__ __forceinline__ unsigned bf16rne(float f) {
    unsigned u = __float_as_uint(f);
    return (u + 0x7FFFu + ((u >> 16) & 1u)) >> 16;   // round-to-nearest-even
}
__device__ __forceinline__ unsigned pack2(float lo, float hi) {
    return bf16rne(lo) | (bf16rne(hi) << 16);
}

// Pb[ir*NZ+iz] = { pack(Q11,Q21), pack(Q12,Q22) }
//   Q11=tt[ir,iz] Q21=tt[ir+1,iz] Q12=tt[ir,iz+1] Q22=tt[ir+1,iz+1]
__global__ void __launch_bounds__(256) build_bf16(
    const float* __restrict__ tt, uv2* __restrict__ Pb) {
    int i = blockIdx.x * 256 + threadIdx.x;
    if (i >= P_ELEMS) return;
    int ir = i >> 9;              // NZ = 512
    int iz = i & 511;
    int izc = min(iz, NZ - 2);    // slot iz=511 never queried; avoid OOB
    float q11 = tt[(ir << 9) + izc];
    float q12 = tt[(ir << 9) + izc + 1];
    float q21 = tt[((ir + 1) << 9) + izc];
    float q22 = tt[((ir + 1) << 9) + izc + 1];
    uv2 v;
    v.x = pack2(q11, q21);
    v.y = pack2(q12, q22);
    Pb[i] = v;
}

// NOTE (measured, rounds 1-3): the single 8B gather below runs at the per-CU
// divergent-address service rate (~3.6 cy/addr). Deeper MLP (r1) and L1-bypass
// via sc0 agent-scope loads (r3) were both flat-to-negative — the plain cached
// load is the best measured variant. Do not "optimize" the gather path without
// new counter evidence.
__device__ __forceinline__ int cell_addr(float rr, float zz) {
    // trunc-cast == floor for rr >= 0; for rr < 0 both paths clamp to 0 and
    // the weight formula matches the reference's clipped-index semantics.
    int ir0 = min(max((int)rr, 0), NR - 2);
    int iz0 = min(max((int)zz, 0), NZ - 2);
    return (ir0 << 9) + iz0;
}

__device__ __forceinline__ float combine(float rr, float zz, uv2 g) {
    int ir0 = min(max((int)rr, 0), NR - 2);
    int iz0 = min(max((int)zz, 0), NZ - 2);
    float dx = rr - (float)ir0;
    float dz = zz - (float)iz0;
    float wx = 1.0f - dx;
    float wz = 1.0f - dz;
    float f11 = __uint_as_float(g.x << 16);
    float f21 = __uint_as_float(g.x & 0xFFFF0000u);
    float f12 = __uint_as_float(g.y << 16);
    float f22 = __uint_as_float(g.y & 0xFFFF0000u);
    return wx * (f11 * wz + f12 * dz) + dx * (f21 * wz + f22 * dz);
}

__global__ void __launch_bounds__(BLOCK, 4) interp_bf16(
    const float* __restrict__ r, const float* __restrict__ z,
    const uv2* __restrict__ Pb, float* __restrict__ out, int nvec) {
    const int tid = threadIdx.x;
    const int base = blockIdx.x * (BLOCK * VPT) + tid;
    const bool full = (blockIdx.x + 1) * (BLOCK * VPT) <= nvec;

    if (full) {
        // Phase 0: stream in 16 queries (nontemporal: don't pollute L2,
        // keep the gather table resident there).
        vf4 rv[VPT], zv[VPT];
#pragma unroll
        for (int k = 0; k < VPT; ++k) {
            rv[k] = __builtin_nontemporal_load(
                reinterpret_cast<const vf4*>(r) + base + k * BLOCK);
            zv[k] = __builtin_nontemporal_load(
                reinterpret_cast<const vf4*>(z) + base + k * BLOCK);
        }
        // Phase 1: issue all 16 gathers back-to-back (plain cached loads).
        uv2 g[VPT][4];
#pragma unroll
        for (int k = 0; k < VPT; ++k) {
            g[k][0] = Pb[cell_addr(rv[k].x, zv[k].x)];
            g[k][1] = Pb[cell_addr(rv[k].y, zv[k].y)];
            g[k][2] = Pb[cell_addr(rv[k].z, zv[k].z)];
            g[k][3] = Pb[cell_addr(rv[k].w, zv[k].w)];
        }
        // Phase 2: recompute weights (cheap VALU) and combine.
#pragma unroll
        for (int k = 0; k < VPT; ++k) {
            vf4 o;
            o.x = combine(rv[k].x, zv[k].x, g[k][0]);
            o.y = combine(rv[k].y, zv[k].y, g[k][1]);
            o.z = combine(rv[k].z, zv[k].z, g[k][2]);
            o.w = combine(rv[k].w, zv[k].w, g[k][3]);
            __builtin_nontemporal_store(
                o, reinterpret_cast<vf4*>(out) + base + k * BLOCK);
        }
    } else {
#pragma unroll
        for (int k = 0; k < VPT; ++k) {
            const int gv = base + k * BLOCK;
            if (gv < nvec) {
                vf4 rv = reinterpret_cast<const vf4*>(r)[gv];
                vf4 zv = reinterpret_cast<const vf4*>(z)[gv];
                uv2 g0 = Pb[cell_addr(rv.x, zv.x)];
                uv2 g1 = Pb[cell_addr(rv.y, zv.y)];
                uv2 g2 = Pb[cell_addr(rv.z, zv.z)];
                uv2 g3 = Pb[cell_addr(rv.w, zv.w)];
                vf4 o;
                o.x = combine(rv.x, zv.x, g0);
                o.y = combine(rv.y, zv.y, g1);
                o.z = combine(rv.z, zv.z, g2);
                o.w = combine(rv.w, zv.w, g3);
                reinterpret_cast<vf4*>(out)[gv] = o;
            }
        }
    }
}

// ---- exact-fp32 scalar tail + fallback path ----
__device__ __forceinline__ float interp_direct(float rr, float zz,
                                               const float* __restrict__ tt) {
    int ir0 = (int)floorf(rr);
    int iz0 = (int)floorf(zz);
    ir0 = min(max(ir0, 0), NR - 2);
    iz0 = min(max(iz0, 0), NZ - 2);
    float dx = rr - (float)ir0, wx = 1.0f - dx;
    float dz = zz - (float)iz0, wz = 1.0f - dz;
    int b = (ir0 << 9) + iz0;
    float Q11 = tt[b], Q12 = tt[b + 1], Q21 = tt[b + NZ], Q22 = tt[b + NZ + 1];
    return (Q11 * wz + Q12 * dz) * wx + (Q21 * wz + Q22 * dz) * dx;
}

__global__ void tail_direct(const float* __restrict__ r, const float* __restrict__ z,
                            const float* __restrict__ tt, float* __restrict__ out,
                            int start, int n) {
    int j = start + blockIdx.x * blockDim.x + threadIdx.x;
    if (j < n) out[j] = interp_direct(r[j], z[j], tt);
}

__global__ void __launch_bounds__(256) interp_direct_kernel(
    const float* __restrict__ r, const float* __restrict__ z,
    const float* __restrict__ tt, float* __restrict__ out, int n4) {
    int i = blockIdx.x * blockDim.x + threadIdx.x;
    if (i < n4) {
        vf4 rv = reinterpret_cast<const vf4*>(r)[i];
        vf4 zv = reinterpret_cast<const vf4*>(z)[i];
        vf4 o;
        o.x = interp_direct(rv.x, zv.x, tt);
        o.y = interp_direct(rv.y, zv.y, tt);
        o.z = interp_direct(rv.z, zv.z, tt);
        o.w = interp_direct(rv.w, zv.w, tt);
        reinterpret_cast<vf4*>(out)[i] = o;
    }
}

extern "C" void kernel_launch(void* const* d_in, const int* in_sizes, int n_in,
                              void* d_out, int out_size, void* d_ws, size_t ws_size,
                              hipStream_t stream) {
    const float* r  = (const float*)d_in[0];
    const float* z  = (const float*)d_in[1];
    const float* tt = (const float*)d_in[2];
    float* out = (float*)d_out;
    const int n = in_sizes[0];
    const int nvec = n / 4;
    const int tail = n - nvec * 4;

    const size_t need = (size_t)P_ELEMS * sizeof(uv2);   // ~2.09 MB
    if (ws_size >= need) {
        uv2* Pb = (uv2*)d_ws;
        build_bf16<<<(P_ELEMS + 255) / 256, 256, 0, stream>>>(tt, Pb);
        const int blocks = (nvec + BLOCK * VPT - 1) / (BLOCK * VPT);
        interp_bf16<<<blocks, BLOCK, 0, stream>>>(r, z, Pb, out, nvec);
    } else {
        interp_direct_kernel<<<(nvec + 255) / 256, 256, 0, stream>>>(r, z, tt, out, nvec);
    }
    if (tail > 0)
        tail_direct<<<1, 64, 0, stream>>>(r, z, tt, out, nvec * 4, n);
}